// Round 16
// baseline (102.779 us; speedup 1.0000x reference)
//
#include <hip/hip_runtime.h>
#include <hip/hip_fp16.h>
#include <math.h>

#define NN 100000   // N
#define NF 10       // n features
#define MC 8        // M_CLUSTERS
#define KK 16       // K neighbours
#define BB 4        // batch
#define MUF 20.0f

#define ESL 50                        // enc slices per c
#define ECH (NN / ESL)                // 2000 elements per slice (16B-aligned starts)
#define ENC_BLOCKS (NF * ESL)         // 500 (c, slice) blocks, 4 batch-acc each
#define TRB ((NN + 255) / 256)        // 391 transpose blocks

__device__ __forceinline__ float frcp(float x) {
#if __has_builtin(__builtin_amdgcn_rcpf)
    return __builtin_amdgcn_rcpf(x);   // v_rcp_f32; wsum >= 7 so safe
#else
    return 1.0f / x;
#endif
}

// ---- Kernel A: enc partials keyed (c,slice), Wenc read once/block + transpose ----
// blocks [0,500): c = blk/50, slice = blk%50 -> part[blk*4 + b] for b=0..3
// blocks [500,891): transpose W_dec (n,N) -> Wt16 (N rows x 32B: 10 halfs + pad)
template <bool TR>
__global__ __launch_bounds__(256) void k_prep(const float* __restrict__ x,
                                              const float* __restrict__ Wenc,
                                              const float* __restrict__ Wdec,
                                              float* __restrict__ part,
                                              __half* __restrict__ Wt16) {
    int blk = blockIdx.x;
    if (blk < ENC_BLOCKS) {
        int c = blk / ESL, slice = blk % ESL;
        int j0 = slice * ECH;                 // 2000-elem slices -> 16B aligned
        int j1 = j0 + ECH;
        const float* wp = Wenc + (size_t)c * NN;
        float4 a[BB];
#pragma unroll
        for (int b = 0; b < BB; ++b) a[b] = make_float4(0.f, 0.f, 0.f, 0.f);
        for (int j = j0 + (threadIdx.x << 2); j < j1; j += 1024) {
            float4 wv = *(const float4*)(wp + j);
#pragma unroll
            for (int b = 0; b < BB; ++b) {
                float4 xv = *(const float4*)(x + (size_t)b * NN + j);
                a[b].x = fmaf(xv.x, wv.x, a[b].x);
                a[b].y = fmaf(xv.y, wv.y, a[b].y);
                a[b].z = fmaf(xv.z, wv.z, a[b].z);
                a[b].w = fmaf(xv.w, wv.w, a[b].w);
            }
        }
        float s[BB];
#pragma unroll
        for (int b = 0; b < BB; ++b) {
            float v = (a[b].x + a[b].y) + (a[b].z + a[b].w);
#pragma unroll
            for (int off = 32; off; off >>= 1) v += __shfl_down(v, off, 64);
            s[b] = v;
        }
        __shared__ float red[4][BB];
        int lane = threadIdx.x & 63, w = threadIdx.x >> 6;
        if (lane == 0) {
#pragma unroll
            for (int b = 0; b < BB; ++b) red[w][b] = s[b];
        }
        __syncthreads();
        if (threadIdx.x < BB)
            part[(blk << 2) + threadIdx.x] = red[0][threadIdx.x] + red[1][threadIdx.x] +
                                             red[2][threadIdx.x] + red[3][threadIdx.x];
    } else if (TR) {
        int j = (blk - ENC_BLOCKS) * 256 + threadIdx.x;
        if (j < NN) {
            union { __half h[8]; float4 f4; } u0;
            union { __half h[2]; float  f;  } u1;
#pragma unroll
            for (int c = 0; c < 8; ++c) u0.h[c] = __float2half(Wdec[(size_t)c * NN + j]);
            u1.h[0] = __float2half(Wdec[(size_t)8 * NN + j]);
            u1.h[1] = __float2half(Wdec[(size_t)9 * NN + j]);
            __half* row = Wt16 + (size_t)j * 16;    // 32B stride, never line-straddles
            *(float4*)row = u0.f4;
            ((float*)row)[4] = u1.f;
        }
    }
}

// ---- Kernel B: prologue (enc+dinv in LDS) + fused main (bh-split) ----
// thread g: j = g>>1, handles b = {bh, bh+1} where bh = (g&1)*2.
// Lane pairs share j so gather addresses dedup within the wave.
// Gather: 2 loads/neighbor (16B + 4B) from fp16 Wt rows (32B, L2-resident 3.2 MB).
template <bool TR>
__global__ __launch_bounds__(256) void k_main(const float* __restrict__ ndist,
                                              const int* __restrict__ nbid,
                                              const int* __restrict__ labels,
                                              const float* __restrict__ part,
                                              const float* __restrict__ Wbw,
                                              const __half* __restrict__ Wt16,
                                              const float* __restrict__ Wdec,
                                              float* __restrict__ out) {
    __shared__ float s_enc[BB * NF];         // 40
    __shared__ float s_dinv[BB * NF * MC];   // 320
    int tid = threadIdx.x;
    if (tid < BB * NF) {
        int b = tid / NF, c = tid - b * NF;  // s_enc layout [b*NF+c]
        float s = 0.f;
#pragma unroll
        for (int i = 0; i < ESL; ++i) s += part[(((c * ESL) + i) << 2) + b];
        s_enc[tid] = s;
    }
    __syncthreads();
    for (int t = tid; t < BB * NF * MC; t += 256) {
        int b = t / (NF * MC);
        int r = t % (NF * MC);               // r = c*MC + m
        float z = 0.f;
#pragma unroll
        for (int c = 0; c < NF; ++c) z = fmaf(s_enc[b * NF + c], Wbw[r * NF + c], z);
        float sig = 1.f / (1.f + __expf(-z));
        const float lo = (float)(4.0 / 60.0 / 20.0);
        const float sc = (float)(1.0 / 60.0 - 4.0 / 60.0 / 20.0);
        float bwv = fmaf(sc, sig, lo) * MUF;
        s_dinv[t] = frcp(bwv * bwv);
    }
    __syncthreads();

    int g = blockIdx.x * 256 + tid;
    int j = g >> 1;
    if (j >= NN) return;
    int bh = (g & 1) << 1;                   // 0 or 2

    int lab = labels[j];
    float dA[NF], dB[NF];
#pragma unroll
    for (int c = 0; c < NF; ++c) {
        dA[c] = s_dinv[(bh)     * (NF * MC) + c * MC + lab];
        dB[c] = s_dinv[(bh + 1) * (NF * MC) + c * MC + lab];
    }

    const float4* dp = (const float4*)(ndist + (size_t)j * KK);
    float4 q0 = dp[0], q1 = dp[1], q2 = dp[2], q3 = dp[3];
    const int4* np = (const int4*)(nbid + (size_t)j * KK);
    int4 i0 = np[0], i1 = np[1], i2 = np[2], i3 = np[3];
    float nd[KK] = {q0.x, q0.y, q0.z, q0.w, q1.x, q1.y, q1.z, q1.w,
                    q2.x, q2.y, q2.z, q2.w, q3.x, q3.y, q3.z, q3.w};
    int nb[KK] = {i0.x, i0.y, i0.z, i0.w, i1.x, i1.y, i1.z, i1.w,
                  i2.x, i2.y, i2.z, i2.w, i3.x, i3.y, i3.z, i3.w};

    float wsA[NF], smA[NF], wsB[NF], smB[NF];
#pragma unroll
    for (int c = 0; c < NF; ++c) { wsA[c] = 0.f; smA[c] = 0.f; wsB[c] = 0.f; smB[c] = 0.f; }

#pragma unroll
    for (int k = 0; k < KK; ++k) {
        float d = nd[k];
        float dd = d * d;
        float bas[NF];
        if (TR) {
            const float4* bp = (const float4*)(Wt16 + (size_t)(unsigned)nb[k] * 16);
            float4 w0 = bp[0];                      // halfs 0..7
            float  w1 = ((const float*)bp)[4];      // halfs 8..9
            union { float4 f4; __half2 h2[4]; } ua; ua.f4 = w0;
            union { float  f;  __half2 h2;    } ub; ub.f  = w1;
            float2 p;
            p = __half22float2(ua.h2[0]); bas[0] = p.x; bas[1] = p.y;
            p = __half22float2(ua.h2[1]); bas[2] = p.x; bas[3] = p.y;
            p = __half22float2(ua.h2[2]); bas[4] = p.x; bas[5] = p.y;
            p = __half22float2(ua.h2[3]); bas[6] = p.x; bas[7] = p.y;
            p = __half22float2(ub.h2);    bas[8] = p.x; bas[9] = p.y;
        } else {
#pragma unroll
            for (int c = 0; c < NF; ++c) bas[c] = Wdec[(size_t)c * NN + (unsigned)nb[k]];
        }
#pragma unroll
        for (int c = 0; c < NF; ++c) {
            float wA = fmaxf(fmaf(-dd, dA[c], 1.f), 0.f);
            wsA[c] += wA; smA[c] = fmaf(wA, bas[c], smA[c]);
            float wB = fmaxf(fmaf(-dd, dB[c], 1.f), 0.f);
            wsB[c] += wB; smB[c] = fmaf(wB, bas[c], smB[c]);
        }
    }

    float accA = 0.f, accB = 0.f;
#pragma unroll
    for (int c = 0; c < NF; ++c) {
        accA = fmaf(s_enc[bh * NF + c],       smA[c] * frcp(wsA[c]), accA);
        accB = fmaf(s_enc[(bh + 1) * NF + c], smB[c] * frcp(wsB[c]), accB);
    }
    out[(size_t)bh * NN + j]       = accA;
    out[(size_t)(bh + 1) * NN + j] = accB;
}

extern "C" void kernel_launch(void* const* d_in, const int* in_sizes, int n_in,
                              void* d_out, int out_size, void* d_ws, size_t ws_size,
                              hipStream_t stream) {
    const float* x      = (const float*)d_in[0];
    const float* Wenc   = (const float*)d_in[1];
    const float* Wdec   = (const float*)d_in[2];
    const float* Wbw    = (const float*)d_in[3];
    const float* ndist  = (const float*)d_in[4];
    const int*   nbid   = (const int*)d_in[5];
    const int*   labels = (const int*)d_in[6];
    float* out = (float*)d_out;

    float*  part = (float*)d_ws;                      // 500*4 floats
    __half* Wt16 = (__half*)((char*)d_ws + 32768);    // N*16 halfs (3.2 MB)
    size_t need = 32768 + (size_t)NN * 16 * sizeof(__half);
    bool tr = (ws_size >= need);

    int main_blocks = (NN * 2 + 255) / 256;           // 782

    if (tr) {
        k_prep<true><<<ENC_BLOCKS + TRB, 256, 0, stream>>>(x, Wenc, Wdec, part, Wt16);
        k_main<true><<<main_blocks, 256, 0, stream>>>(ndist, nbid, labels, part, Wbw, Wt16, Wdec, out);
    } else {
        k_prep<false><<<ENC_BLOCKS, 256, 0, stream>>>(x, Wenc, Wdec, part, nullptr);
        k_main<false><<<main_blocks, 256, 0, stream>>>(ndist, nbid, labels, part, Wbw, nullptr, Wdec, out);
    }
}

// Round 17
// 100.663 us; speedup vs baseline: 1.0210x; 1.0210x over previous
//
#include <hip/hip_runtime.h>
#include <hip/hip_fp16.h>
#include <math.h>

#define NN 100000   // N
#define NF 10       // n features
#define MC 8        // M_CLUSTERS
#define KK 16       // K neighbours
#define BB 4        // batch
#define MUF 20.0f

#define ESL 25                        // enc slices per (b,c) pair
#define ECH (NN / ESL)                // 4000 elements per slice (16B-aligned starts)
#define ENC_BLOCKS (BB * NF * ESL)    // 1000
#define TRB ((NN + 255) / 256)        // 391 transpose blocks

__device__ __forceinline__ float frcp(float x) {
#if __has_builtin(__builtin_amdgcn_rcpf)
    return __builtin_amdgcn_rcpf(x);   // v_rcp_f32; wsum >= 7 so safe
#else
    return 1.0f / x;
#endif
}

// ---- Kernel A: enc partial sums (float4 loads) + W_dec transpose->fp16 ----
// blocks [0,1000): pair = blk/25, slice = blk%25 -> part[pair*25+slice]
// blocks [1000,1391): transpose W_dec (n,N) -> Wt16 (N rows x 32B: 10 halfs + pad)
template <bool TR>
__global__ __launch_bounds__(256) void k_prep(const float* __restrict__ x,
                                              const float* __restrict__ Wenc,
                                              const float* __restrict__ Wdec,
                                              float* __restrict__ part,
                                              __half* __restrict__ Wt16) {
    int blk = blockIdx.x;
    if (blk < ENC_BLOCKS) {
        int pair  = blk / ESL;
        int slice = blk % ESL;
        int b = pair / NF, c = pair % NF;
        int j0 = slice * ECH;                 // multiple of 4000 -> 16B aligned
        int j1 = j0 + ECH;
        const float* xp = x + (size_t)b * NN;
        const float* wp = Wenc + (size_t)c * NN;
        float a0 = 0.f, a1 = 0.f, a2 = 0.f, a3 = 0.f;
        for (int j = j0 + (threadIdx.x << 2); j < j1; j += 1024) {
            float4 xv = *(const float4*)(xp + j);
            float4 wv = *(const float4*)(wp + j);
            a0 = fmaf(xv.x, wv.x, a0);
            a1 = fmaf(xv.y, wv.y, a1);
            a2 = fmaf(xv.z, wv.z, a2);
            a3 = fmaf(xv.w, wv.w, a3);
        }
        float acc = (a0 + a1) + (a2 + a3);
#pragma unroll
        for (int off = 32; off; off >>= 1) acc += __shfl_down(acc, off, 64);
        __shared__ float red[4];
        if ((threadIdx.x & 63) == 0) red[threadIdx.x >> 6] = acc;
        __syncthreads();
        if (threadIdx.x == 0) part[blk] = red[0] + red[1] + red[2] + red[3];
    } else if (TR) {
        int j = (blk - ENC_BLOCKS) * 256 + threadIdx.x;
        if (j < NN) {
            union { __half h[8]; float4 f4; } u0;
            union { __half h[2]; float  f;  } u1;
#pragma unroll
            for (int c = 0; c < 8; ++c) u0.h[c] = __float2half(Wdec[(size_t)c * NN + j]);
            u1.h[0] = __float2half(Wdec[(size_t)8 * NN + j]);
            u1.h[1] = __float2half(Wdec[(size_t)9 * NN + j]);
            __half* row = Wt16 + (size_t)j * 16;    // 32B stride, never line-straddles
            *(float4*)row = u0.f4;
            ((float*)row)[4] = u1.f;
        }
    }
}

// ---- Kernel B: prologue (enc+dinv in LDS) + fused main (bh-split) ----
// thread g: j = g>>1, handles b = {bh, bh+1} where bh = (g&1)*2.
// Lane pairs share j so gather addresses dedup within the wave.
// Gather: 2 loads/neighbor (16B + 4B) from fp16 Wt rows (32B, L2-resident 3.2 MB).
template <bool TR>
__global__ __launch_bounds__(256) void k_main(const float* __restrict__ ndist,
                                              const int* __restrict__ nbid,
                                              const int* __restrict__ labels,
                                              const float* __restrict__ part,
                                              const float* __restrict__ Wbw,
                                              const __half* __restrict__ Wt16,
                                              const float* __restrict__ Wdec,
                                              float* __restrict__ out) {
    __shared__ float s_enc[BB * NF];         // 40
    __shared__ float s_dinv[BB * NF * MC];   // 320
    int tid = threadIdx.x;
    if (tid < BB * NF) {
        const float* p = part + tid * ESL;
        float s = 0.f;
#pragma unroll
        for (int i = 0; i < ESL; ++i) s += p[i];
        s_enc[tid] = s;
    }
    __syncthreads();
    for (int t = tid; t < BB * NF * MC; t += 256) {
        int b = t / (NF * MC);
        int r = t % (NF * MC);               // r = c*MC + m
        float z = 0.f;
#pragma unroll
        for (int c = 0; c < NF; ++c) z = fmaf(s_enc[b * NF + c], Wbw[r * NF + c], z);
        float sig = 1.f / (1.f + __expf(-z));
        const float lo = (float)(4.0 / 60.0 / 20.0);
        const float sc = (float)(1.0 / 60.0 - 4.0 / 60.0 / 20.0);
        float bwv = fmaf(sc, sig, lo) * MUF;
        s_dinv[t] = frcp(bwv * bwv);
    }
    __syncthreads();

    int g = blockIdx.x * 256 + tid;
    int j = g >> 1;
    if (j >= NN) return;
    int bh = (g & 1) << 1;                   // 0 or 2

    int lab = labels[j];
    float dA[NF], dB[NF];
#pragma unroll
    for (int c = 0; c < NF; ++c) {
        dA[c] = s_dinv[(bh)     * (NF * MC) + c * MC + lab];
        dB[c] = s_dinv[(bh + 1) * (NF * MC) + c * MC + lab];
    }

    const float4* dp = (const float4*)(ndist + (size_t)j * KK);
    float4 q0 = dp[0], q1 = dp[1], q2 = dp[2], q3 = dp[3];
    const int4* np = (const int4*)(nbid + (size_t)j * KK);
    int4 i0 = np[0], i1 = np[1], i2 = np[2], i3 = np[3];
    float nd[KK] = {q0.x, q0.y, q0.z, q0.w, q1.x, q1.y, q1.z, q1.w,
                    q2.x, q2.y, q2.z, q2.w, q3.x, q3.y, q3.z, q3.w};
    int nb[KK] = {i0.x, i0.y, i0.z, i0.w, i1.x, i1.y, i1.z, i1.w,
                  i2.x, i2.y, i2.z, i2.w, i3.x, i3.y, i3.z, i3.w};

    float wsA[NF], smA[NF], wsB[NF], smB[NF];
#pragma unroll
    for (int c = 0; c < NF; ++c) { wsA[c] = 0.f; smA[c] = 0.f; wsB[c] = 0.f; smB[c] = 0.f; }

#pragma unroll
    for (int k = 0; k < KK; ++k) {
        float d = nd[k];
        float dd = d * d;
        float bas[NF];
        if (TR) {
            const float4* bp = (const float4*)(Wt16 + (size_t)(unsigned)nb[k] * 16);
            float4 w0 = bp[0];                      // halfs 0..7
            float  w1 = ((const float*)bp)[4];      // halfs 8..9
            union { float4 f4; __half2 h2[4]; } ua; ua.f4 = w0;
            union { float  f;  __half2 h2;    } ub; ub.f  = w1;
            float2 p;
            p = __half22float2(ua.h2[0]); bas[0] = p.x; bas[1] = p.y;
            p = __half22float2(ua.h2[1]); bas[2] = p.x; bas[3] = p.y;
            p = __half22float2(ua.h2[2]); bas[4] = p.x; bas[5] = p.y;
            p = __half22float2(ua.h2[3]); bas[6] = p.x; bas[7] = p.y;
            p = __half22float2(ub.h2);    bas[8] = p.x; bas[9] = p.y;
        } else {
#pragma unroll
            for (int c = 0; c < NF; ++c) bas[c] = Wdec[(size_t)c * NN + (unsigned)nb[k]];
        }
#pragma unroll
        for (int c = 0; c < NF; ++c) {
            float wA = fmaxf(fmaf(-dd, dA[c], 1.f), 0.f);
            wsA[c] += wA; smA[c] = fmaf(wA, bas[c], smA[c]);
            float wB = fmaxf(fmaf(-dd, dB[c], 1.f), 0.f);
            wsB[c] += wB; smB[c] = fmaf(wB, bas[c], smB[c]);
        }
    }

    float accA = 0.f, accB = 0.f;
#pragma unroll
    for (int c = 0; c < NF; ++c) {
        accA = fmaf(s_enc[bh * NF + c],       smA[c] * frcp(wsA[c]), accA);
        accB = fmaf(s_enc[(bh + 1) * NF + c], smB[c] * frcp(wsB[c]), accB);
    }
    out[(size_t)bh * NN + j]       = accA;
    out[(size_t)(bh + 1) * NN + j] = accB;
}

extern "C" void kernel_launch(void* const* d_in, const int* in_sizes, int n_in,
                              void* d_out, int out_size, void* d_ws, size_t ws_size,
                              hipStream_t stream) {
    const float* x      = (const float*)d_in[0];
    const float* Wenc   = (const float*)d_in[1];
    const float* Wdec   = (const float*)d_in[2];
    const float* Wbw    = (const float*)d_in[3];
    const float* ndist  = (const float*)d_in[4];
    const int*   nbid   = (const int*)d_in[5];
    const int*   labels = (const int*)d_in[6];
    float* out = (float*)d_out;

    float*  part = (float*)d_ws;                      // 1000 floats
    __half* Wt16 = (__half*)((char*)d_ws + 32768);    // N*16 halfs (3.2 MB)
    size_t need = 32768 + (size_t)NN * 16 * sizeof(__half);
    bool tr = (ws_size >= need);

    int main_blocks = (NN * 2 + 255) / 256;           // 782

    if (tr) {
        k_prep<true><<<ENC_BLOCKS + TRB, 256, 0, stream>>>(x, Wenc, Wdec, part, Wt16);
        k_main<true><<<main_blocks, 256, 0, stream>>>(ndist, nbid, labels, part, Wbw, Wt16, Wdec, out);
    } else {
        k_prep<false><<<ENC_BLOCKS, 256, 0, stream>>>(x, Wenc, Wdec, part, nullptr);
        k_main<false><<<main_blocks, 256, 0, stream>>>(ndist, nbid, labels, part, Wbw, nullptr, Wdec, out);
    }
}